// Round 1
// baseline (12444.987 us; speedup 1.0000x reference)
//
#include <hip/hip_runtime.h>
#include <math.h>

#define B_ 64
#define T_ 256
#define D_ 300
#define H_ 512
#define G4_ 2048   // 4*H
#define HD_ 1024   // 2*H
#define CH_ 64     // time chunk for xp precompute

// ---------------- lengths ----------------
__global__ void k_lengths(const int* __restrict__ word, int* __restrict__ lens,
                          int* __restrict__ out_len) {
  __shared__ int s[256];
  int b = blockIdx.x, t = threadIdx.x;
  s[t] = (word[b * T_ + t] > 0) ? 1 : 0;
  __syncthreads();
  for (int off = 128; off > 0; off >>= 1) {
    if (t < off) s[t] += s[t + off];
    __syncthreads();
  }
  if (t == 0) { lens[b] = s[0]; out_len[b] = s[0]; }
}

// ---------------- embedding gather: x (T,B,D) ----------------
__global__ void k_embed(const int* __restrict__ word, const float* __restrict__ emb,
                        float* __restrict__ x) {
  const int D4 = D_ / 4;
  int idx = blockIdx.x * blockDim.x + threadIdx.x;
  if (idx >= T_ * B_ * D4) return;
  int d4 = idx % D4;
  int row = idx / D4;           // row = t*B + b
  int b = row % B_, t = row / B_;
  int w = word[b * T_ + t];
  float4 v = ((const float4*)(emb + (size_t)w * D_))[d4];
  ((float4*)(x + (size_t)row * D_))[d4] = v;
}

// ---------------- projection GEMM: C(CH*B,2048) = A * W^T + bias ----------------
// src: (T,B,K) t-major. If rev: A row (s,b) = src[len[b]-1-s] (zeros if <0).
__global__ __launch_bounds__(256) void k_proj(
    const float* __restrict__ src, const float* __restrict__ W,
    const float* __restrict__ bias, float* __restrict__ C,
    const int* __restrict__ lens, int K, int t0, int rev) {
  __shared__ float As[16][68];
  __shared__ float Ws[16][68];
  int bm = blockIdx.x, bn = blockIdx.y;
  int tid = threadIdx.x;
  int tx = tid & 15, ty = tid >> 4;
  float acc[4][4];
#pragma unroll
  for (int i = 0; i < 4; i++)
#pragma unroll
    for (int j = 0; j < 4; j++) acc[i][j] = 0.f;

  int lr = tid >> 2;        // 0..63 (row of A tile / col of W tile)
  int lk = (tid & 3) * 4;   // 0,4,8,12

  int grow = bm * 64 + lr;          // chunk-local row = tl*B + b
  int b = grow & (B_ - 1), tl = grow >> 6;
  long srow;
  if (!rev) srow = (long)(t0 + tl) * B_ + b;
  else {
    int tp = lens[b] - 1 - (t0 + tl);
    srow = (tp >= 0) ? (long)tp * B_ + b : -1;
  }
  const float* arow = (srow >= 0) ? src + (size_t)srow * K : (const float*)0;
  int wcol = bn * 64 + lr;
  const float* wrow = W + (size_t)wcol * K;

  for (int k0 = 0; k0 < K; k0 += 16) {
    float4 av; av.x = av.y = av.z = av.w = 0.f;
    if (arow) {
      if (k0 + lk + 4 <= K) av = *(const float4*)(arow + k0 + lk);
      else {
        float tv[4] = {0.f, 0.f, 0.f, 0.f};
        for (int q = 0; q < 4; q++) if (k0 + lk + q < K) tv[q] = arow[k0 + lk + q];
        av.x = tv[0]; av.y = tv[1]; av.z = tv[2]; av.w = tv[3];
      }
    }
    float4 wv; wv.x = wv.y = wv.z = wv.w = 0.f;
    if (k0 + lk + 4 <= K) wv = *(const float4*)(wrow + k0 + lk);
    else {
      float tv[4] = {0.f, 0.f, 0.f, 0.f};
      for (int q = 0; q < 4; q++) if (k0 + lk + q < K) tv[q] = wrow[k0 + lk + q];
      wv.x = tv[0]; wv.y = tv[1]; wv.z = tv[2]; wv.w = tv[3];
    }
    __syncthreads();   // protect previous iteration's reads
    As[lk + 0][lr] = av.x; As[lk + 1][lr] = av.y; As[lk + 2][lr] = av.z; As[lk + 3][lr] = av.w;
    Ws[lk + 0][lr] = wv.x; Ws[lk + 1][lr] = wv.y; Ws[lk + 2][lr] = wv.z; Ws[lk + 3][lr] = wv.w;
    __syncthreads();
#pragma unroll
    for (int k = 0; k < 16; k++) {
      float4 a4 = *(const float4*)&As[k][ty * 4];
      float4 b4 = *(const float4*)&Ws[k][tx * 4];
      acc[0][0] += a4.x * b4.x; acc[0][1] += a4.x * b4.y; acc[0][2] += a4.x * b4.z; acc[0][3] += a4.x * b4.w;
      acc[1][0] += a4.y * b4.x; acc[1][1] += a4.y * b4.y; acc[1][2] += a4.y * b4.z; acc[1][3] += a4.y * b4.w;
      acc[2][0] += a4.z * b4.x; acc[2][1] += a4.z * b4.y; acc[2][2] += a4.z * b4.z; acc[2][3] += a4.z * b4.w;
      acc[3][0] += a4.w * b4.x; acc[3][1] += a4.w * b4.y; acc[3][2] += a4.w * b4.z; acc[3][3] += a4.w * b4.w;
    }
  }
#pragma unroll
  for (int i = 0; i < 4; i++) {
    int row = bm * 64 + ty * 4 + i;
#pragma unroll
    for (int j = 0; j < 4; j++) {
      int col = bn * 64 + tx * 4 + j;
      C[(size_t)row * G4_ + col] = acc[i][j] + bias[col];
    }
  }
}

// ---------------- one LSTM timestep (both directions) ----------------
// grid 256: wg>>7 = dir, (wg&127)*4 = u0. Tile: 64 batch x 16 gate-cols, K=512.
__global__ __launch_bounds__(256) void k_step(
    const float* __restrict__ xpf, const float* __restrict__ xpr,
    const float* __restrict__ whh, const int* __restrict__ lens,
    const float* __restrict__ h_in, float* __restrict__ h_out,
    float* __restrict__ cbuf, float* __restrict__ out, int t) {
  int wg = blockIdx.x;
  int dir = wg >> 7;
  int u0 = (wg & 127) * 4;
  int tid = threadIdx.x;
  int tl = t & (CH_ - 1);

  const float* xp = (dir == 0 ? xpf : xpr) + (size_t)tl * B_ * G4_;
  const float* Wh = whh + (size_t)dir * G4_ * H_;
  const float* hi = h_in + (size_t)dir * B_ * H_;
  float* ho = h_out + (size_t)dir * B_ * H_;
  float* cc = cbuf + (size_t)dir * B_ * H_;

  __shared__ float As[64][68];   // [k][b]
  __shared__ float Ws[64][20];   // [k][c]

  int c = tid & 15;
  int b0 = (tid >> 4) * 4;
  int g = c >> 2, j = c & 3;
  int grow = g * H_ + u0 + j;

  float a0 = 0.f, a1 = 0.f, a2 = 0.f, a3 = 0.f;

  for (int k0 = 0; k0 < H_; k0 += 64) {
    // load h tile: 64b x 64k; thread: one b row, 16 consecutive k
    {
      int bb = tid >> 2;
      int kk = (tid & 3) * 16;
      const float* p = hi + (size_t)bb * H_ + k0 + kk;
      float4 v0 = *(const float4*)(p + 0);
      float4 v1 = *(const float4*)(p + 4);
      float4 v2 = *(const float4*)(p + 8);
      float4 v3 = *(const float4*)(p + 12);
      __syncthreads();
      As[kk + 0][bb] = v0.x; As[kk + 1][bb] = v0.y; As[kk + 2][bb] = v0.z; As[kk + 3][bb] = v0.w;
      As[kk + 4][bb] = v1.x; As[kk + 5][bb] = v1.y; As[kk + 6][bb] = v1.z; As[kk + 7][bb] = v1.w;
      As[kk + 8][bb] = v2.x; As[kk + 9][bb] = v2.y; As[kk +10][bb] = v2.z; As[kk +11][bb] = v2.w;
      As[kk +12][bb] = v3.x; As[kk +13][bb] = v3.y; As[kk +14][bb] = v3.z; As[kk +15][bb] = v3.w;
    }
    // load W tile: 16 gate rows x 64 k; thread: 4 consecutive k
    {
      int c2 = tid >> 4;
      int kk = (tid & 15) * 4;
      int gr2 = (c2 >> 2) * H_ + u0 + (c2 & 3);
      float4 v = *(const float4*)(Wh + (size_t)gr2 * H_ + k0 + kk);
      Ws[kk + 0][c2] = v.x; Ws[kk + 1][c2] = v.y; Ws[kk + 2][c2] = v.z; Ws[kk + 3][c2] = v.w;
    }
    __syncthreads();
#pragma unroll 8
    for (int k = 0; k < 64; k++) {
      float4 a4 = *(const float4*)&As[k][b0];
      float w = Ws[k][c];
      a0 += a4.x * w; a1 += a4.y * w; a2 += a4.z * w; a3 += a4.w * w;
    }
  }
  __syncthreads();
  // stash gates (+xp) to LDS, reusing As: gl[c][b]
  float* gl = &As[0][0];
  gl[c * 68 + b0 + 0] = a0 + xp[(size_t)(b0 + 0) * G4_ + grow];
  gl[c * 68 + b0 + 1] = a1 + xp[(size_t)(b0 + 1) * G4_ + grow];
  gl[c * 68 + b0 + 2] = a2 + xp[(size_t)(b0 + 2) * G4_ + grow];
  gl[c * 68 + b0 + 3] = a3 + xp[(size_t)(b0 + 3) * G4_ + grow];
  __syncthreads();
  // gate fusion: thread -> (b, jj)
  int b = tid & 63;
  int jj = tid >> 6;
  int u = u0 + jj;
  float iv = gl[(0 * 4 + jj) * 68 + b];
  float fv = gl[(1 * 4 + jj) * 68 + b];
  float gv = gl[(2 * 4 + jj) * 68 + b];
  float ov = gl[(3 * 4 + jj) * 68 + b];
  int len = lens[b];
  float c_old = cc[(size_t)b * H_ + u];
  float h_old = hi[(size_t)b * H_ + u];
  if (t < len) {
    float si = 1.f / (1.f + expf(-iv));
    float sf = 1.f / (1.f + expf(-fv));
    float so = 1.f / (1.f + expf(-ov));
    float cn = sf * c_old + si * tanhf(gv);
    float hn = so * tanhf(cn);
    cc[(size_t)b * H_ + u] = cn;
    ho[(size_t)b * H_ + u] = hn;
    if (dir == 0) out[((size_t)t * B_ + b) * HD_ + u] = hn;
    else          out[((size_t)(len - 1 - t) * B_ + b) * HD_ + H_ + u] = hn;
  } else {
    ho[(size_t)b * H_ + u] = h_old;
    if (dir == 0) out[((size_t)t * B_ + b) * HD_ + u] = 0.f;
  }
}

// ---------------- emission heads ----------------
__global__ void k_em0(const float* __restrict__ o, const float* __restrict__ w,
                      const float* __restrict__ bias, float* __restrict__ em) {
  int gt = blockIdx.x * blockDim.x + threadIdx.x;
  int wid = gt >> 6;
  int lane = threadIdx.x & 63;
  if (wid >= T_ * B_) return;
  const float* row = o + (size_t)wid * HD_;
  float r[16];
#pragma unroll
  for (int q = 0; q < 16; q++) r[q] = row[lane + 64 * q];
  for (int c = 0; c < 13; c++) {
    const float* wr = w + (size_t)c * HD_;
    float p = 0.f;
#pragma unroll
    for (int q = 0; q < 16; q++) p += r[q] * wr[lane + 64 * q];
    for (int off = 32; off > 0; off >>= 1) p += __shfl_down(p, off);
    if (lane == 0) em[(size_t)wid * 16 + c] = p + bias[c];
  }
}

__global__ void k_em1(const float* __restrict__ o, const float* __restrict__ w,
                      const float* __restrict__ bias, const int* __restrict__ tags0,
                      float* __restrict__ em) {
  int gt = blockIdx.x * blockDim.x + threadIdx.x;
  int wid = gt >> 6;
  int lane = threadIdx.x & 63;
  if (wid >= T_ * B_) return;
  int t = wid / B_, b = wid % B_;
  float tag = (float)tags0[b * T_ + t];
  const float* row = o + (size_t)wid * HD_;
  float r[16];
#pragma unroll
  for (int q = 0; q < 16; q++) r[q] = row[lane + 64 * q];
  for (int c = 0; c < 25; c++) {
    const float* wr = w + (size_t)c * 1025;
    float p = 0.f;
#pragma unroll
    for (int q = 0; q < 16; q++) p += r[q] * wr[lane + 64 * q];
    for (int off = 32; off > 0; off >>= 1) p += __shfl_down(p, off);
    if (lane == 0) em[(size_t)wid * 32 + c] = p + wr[1024] * tag + bias[c];
  }
}

// ---------------- Viterbi (one block per batch element) ----------------
template <int L, int LD>
__global__ void k_viterbi(const float* __restrict__ em, const int* __restrict__ lens,
                          const float* __restrict__ startv, const float* __restrict__ endv,
                          const float* __restrict__ trans, int* __restrict__ hist,
                          int* __restrict__ tags) {
  int b = blockIdx.x;
  int j = threadIdx.x;
  __shared__ float sc[L];
  __shared__ float trT[L * L];
  int len = lens[b];
  if (j < L) {
    sc[j] = startv[j] + em[(size_t)b * LD + j];
    for (int i = 0; i < L; i++) trT[j * L + i] = trans[i * L + j];
  }
  __syncthreads();
  for (int t = 1; t < len; t++) {
    float nv = 0.f; int bi = 0;
    if (j < L) {
      float best = sc[0] + trT[j * L + 0];
      for (int i = 1; i < L; i++) {
        float v = sc[i] + trT[j * L + i];
        if (v > best) { best = v; bi = i; }
      }
      nv = best + em[((size_t)t * B_ + b) * LD + j];
      hist[((size_t)b * T_ + t) * LD + j] = bi;
    }
    __syncthreads();
    if (j < L) sc[j] = nv;
    __syncthreads();
  }
  if (j == 0) {
    float best = sc[0] + endv[0]; int bi = 0;
    for (int i = 1; i < L; i++) {
      float v = sc[i] + endv[i];
      if (v > best) { best = v; bi = i; }
    }
    int tag = bi;
    tags[b * T_ + (len - 1)] = tag;
    for (int t = len - 2; t >= 0; t--) {
      tag = hist[((size_t)b * T_ + (t + 1)) * LD + tag];
      tags[b * T_ + t] = tag;
    }
    for (int t = len; t < T_; t++) tags[b * T_ + t] = 0;
  }
}

// ---------------- host ----------------
extern "C" void kernel_launch(void* const* d_in, const int* in_sizes, int n_in,
                              void* d_out, int out_size, void* d_ws, size_t ws_size,
                              hipStream_t stream) {
  const int*   word = (const int*)d_in[0];
  const float* emb  = (const float*)d_in[1];
  const float* w0ih = (const float*)d_in[2];
  const float* w0hh = (const float*)d_in[3];
  const float* b0   = (const float*)d_in[4];
  const float* w1ih = (const float*)d_in[5];
  const float* w1hh = (const float*)d_in[6];
  const float* b1   = (const float*)d_in[7];
  const float* h0w  = (const float*)d_in[8];
  const float* h0b  = (const float*)d_in[9];
  const float* h1w  = (const float*)d_in[10];
  const float* h1b  = (const float*)d_in[11];
  const float* c0s  = (const float*)d_in[12];
  const float* c0e  = (const float*)d_in[13];
  const float* c0t  = (const float*)d_in[14];
  const float* c1s  = (const float*)d_in[15];
  const float* c1e  = (const float*)d_in[16];
  const float* c1t  = (const float*)d_in[17];

  int* out_tags0 = (int*)d_out;
  int* out_tags1 = out_tags0 + B_ * T_;
  int* out_len   = out_tags1 + B_ * T_;

  char* ws = (char*)d_ws;
  size_t off = 0;
  auto alloc = [&](size_t bytes) -> void* {
    void* p = ws + off;
    off += (bytes + 255) & ~(size_t)255;
    return p;
  };
  int*   lens  = (int*)alloc(B_ * 4);
  float* x     = (float*)alloc((size_t)T_ * B_ * D_ * 4);
  float* out0  = (float*)alloc((size_t)T_ * B_ * HD_ * 4);
  float* out1  = (float*)alloc((size_t)T_ * B_ * HD_ * 4);
  float* xpf   = (float*)alloc((size_t)CH_ * B_ * G4_ * 4);
  float* xpr   = (float*)alloc((size_t)CH_ * B_ * G4_ * 4);
  float* hbuf  = (float*)alloc((size_t)2 * 2 * B_ * H_ * 4);
  float* cbuf  = (float*)alloc((size_t)2 * B_ * H_ * 4);
  float* em0   = (float*)alloc((size_t)T_ * B_ * 16 * 4);
  float* em1   = (float*)alloc((size_t)T_ * B_ * 32 * 4);
  int*   hist0 = (int*)alloc((size_t)B_ * T_ * 16 * 4);
  int*   hist1 = (int*)alloc((size_t)B_ * T_ * 32 * 4);
  (void)ws_size; (void)in_sizes; (void)n_in; (void)out_size;

  hipMemsetAsync(out0, 0, (size_t)T_ * B_ * HD_ * 4, stream);
  hipMemsetAsync(out1, 0, (size_t)T_ * B_ * HD_ * 4, stream);

  k_lengths<<<B_, 256, 0, stream>>>(word, lens, out_len);
  {
    int total = T_ * B_ * (D_ / 4);
    k_embed<<<(total + 255) / 256, 256, 0, stream>>>(word, emb, x);
  }

  for (int layer = 0; layer < 2; layer++) {
    const float* src = (layer == 0) ? x : out0;
    int K = (layer == 0) ? D_ : HD_;
    const float* wih = (layer == 0) ? w0ih : w1ih;
    const float* whh = (layer == 0) ? w0hh : w1hh;
    const float* bb  = (layer == 0) ? b0 : b1;
    float* outbuf = (layer == 0) ? out0 : out1;
    hipMemsetAsync(hbuf, 0, (size_t)2 * 2 * B_ * H_ * 4, stream);
    hipMemsetAsync(cbuf, 0, (size_t)2 * B_ * H_ * 4, stream);
    for (int cch = 0; cch < T_ / CH_; cch++) {
      dim3 grid(CH_ * B_ / 64, G4_ / 64);
      k_proj<<<grid, 256, 0, stream>>>(src, wih, bb, xpf, lens, K, cch * CH_, 0);
      k_proj<<<grid, 256, 0, stream>>>(src, wih + (size_t)G4_ * K, bb + G4_, xpr, lens, K, cch * CH_, 1);
      for (int tl = 0; tl < CH_; tl++) {
        int t = cch * CH_ + tl;
        const float* h_in = hbuf + (size_t)(t & 1) * 2 * B_ * H_;
        float* h_out = hbuf + (size_t)((t + 1) & 1) * 2 * B_ * H_;
        k_step<<<256, 256, 0, stream>>>(xpf, xpr, whh, lens, h_in, h_out, cbuf, outbuf, t);
      }
    }
  }

  k_em0<<<(T_ * B_) / 4, 256, 0, stream>>>(out1, h0w, h0b, em0);
  k_viterbi<13, 16><<<B_, 64, 0, stream>>>(em0, lens, c0s, c0e, c0t, hist0, out_tags0);
  k_em1<<<(T_ * B_) / 4, 256, 0, stream>>>(out1, h1w, h1b, out_tags0, em1);
  k_viterbi<25, 32><<<B_, 64, 0, stream>>>(em1, lens, c1s, c1e, c1t, hist1, out_tags1);
}